// Round 10
// baseline (3642.582 us; speedup 1.0000x reference)
//
#include <hip/hip_runtime.h>
#include <hip/hip_bf16.h>
#include <stdint.h>

// Bidirectional 2-layer LSTM decoder: B=16, T=512, E=H=1024.
// Round-10 = R9 sentinel structure + two targeted fixes:
//  1) CANARY polls: full fragment load once; on sentinel-miss spin on ONE
//     dword/lane (rotating over the 8 fragment sub-regions), then re-verify
//     full set. 32x less retry traffic -> MALL un-saturated (R9 FETCH=720MB
//     was mostly poll re-streams at ~13 TB/s chip-wide).
//  2) gl partial buffer padded to 17-float rows (272/gate): kills the 4-way
//     LDS bank conflict (SQ_LDS_BANK_CONFLICT 33.5M).
//  - h0 write-once + 0xFF sentinel, fire-and-forget sc1 stores, no flags.
//  - h1 ring(4) sentinel; reset slot (t+1)&3 at top of step; ordering via the
//    wave's own h0-poll vmcnt(0) (drains reset before epilogue data stores).
//  - Weights: l0 32 frags/wave; l1 32 h0-frags + 4 h1-frags VGPR + 24 ks LDS.

#define TT 512
#define HH 1024

typedef __bf16 bf16x8 __attribute__((ext_vector_type(8)));
typedef float f32x4 __attribute__((ext_vector_type(4)));
typedef unsigned int u32;
typedef unsigned short u16;

#define MFMA __builtin_amdgcn_mfma_f32_16x16x32_bf16

// ---- workspace layout (bytes) ----
#define OFS_B0    4096ul         // [2][4096] f32
#define OFS_B1    36864ul        // [2][4096] f32
#define OFS_X     69632ul        // [8192][1024] bf16
#define OFS_WIH0  16846848ul     // packed [2][64][4][32][64][8] bf16
#define OFS_WHH0  33624064ul     // same shape
#define OFS_W1    50401280ul     // packed [2][64][4][96][64][8] bf16 (h0 64ks | h1 32ks)
#define OFS_H0    100732928ul    // [512][2][16][1024] bf16 (write-once, sentinel-armed)
#define OFS_H1    134287360ul    // [4][2][16][1024] bf16 ring (sentinel protocol)
// end ~134.55 MB

__device__ inline u16 f2b(float f){
  union { float f; u32 u; } x{f};
  return (u16)((x.u + 0x7FFFu + ((x.u >> 16) & 1u)) >> 16);
}
__device__ inline float sigm(float x){ return 1.f/(1.f + __expf(-x)); }
__device__ inline float tanh_(float x){ return 2.f*sigm(2.f*x) - 1.f; }

__device__ inline void g_store32(u32* p, u32 v){
  asm volatile("global_store_dword %0, %1, off sc0 sc1" :: "v"(p), "v"(v) : "memory");
}
__device__ inline u32 g_canary(const u32* p){
  u32 v;
  asm volatile("global_load_dword %0, %1, off sc0 sc1\n\t"
               "s_waitcnt vmcnt(0)" : "=&v"(v) : "v"(p) : "memory");
  return v;
}

// 8x16B coherent loads + single wait
#define G_LOAD8(A, P) asm volatile( \
  "global_load_dwordx4 %0, %8, off sc0 sc1\n\t" \
  "global_load_dwordx4 %1, %8, off offset:64 sc0 sc1\n\t" \
  "global_load_dwordx4 %2, %8, off offset:128 sc0 sc1\n\t" \
  "global_load_dwordx4 %3, %8, off offset:192 sc0 sc1\n\t" \
  "global_load_dwordx4 %4, %8, off offset:256 sc0 sc1\n\t" \
  "global_load_dwordx4 %5, %8, off offset:320 sc0 sc1\n\t" \
  "global_load_dwordx4 %6, %8, off offset:384 sc0 sc1\n\t" \
  "global_load_dwordx4 %7, %8, off offset:448 sc0 sc1\n\t" \
  "s_waitcnt vmcnt(0)" \
  : "=&v"(A[0]), "=&v"(A[1]), "=&v"(A[2]), "=&v"(A[3]), \
    "=&v"(A[4]), "=&v"(A[5]), "=&v"(A[6]), "=&v"(A[7]) \
  : "v"(P) : "memory")

// issue 4x16B sc1 loads WITHOUT waiting
#define G_LOAD4_ISSUE(A, P) asm volatile( \
  "global_load_dwordx4 %0, %4, off sc0 sc1\n\t" \
  "global_load_dwordx4 %1, %4, off offset:64 sc0 sc1\n\t" \
  "global_load_dwordx4 %2, %4, off offset:128 sc0 sc1\n\t" \
  "global_load_dwordx4 %3, %4, off offset:192 sc0 sc1" \
  : "=&v"(A[0]), "=&v"(A[1]), "=&v"(A[2]), "=&v"(A[3]) \
  : "v"(P) : "memory")
#define G_WAIT4(A) asm volatile("s_waitcnt vmcnt(0)" \
  : "+v"(A[0]), "+v"(A[1]), "+v"(A[2]), "+v"(A[3]) :: "memory")
#define G_LOAD4W(A, P) asm volatile( \
  "global_load_dwordx4 %0, %4, off sc0 sc1\n\t" \
  "global_load_dwordx4 %1, %4, off offset:64 sc0 sc1\n\t" \
  "global_load_dwordx4 %2, %4, off offset:128 sc0 sc1\n\t" \
  "global_load_dwordx4 %3, %4, off offset:192 sc0 sc1\n\t" \
  "s_waitcnt vmcnt(0)" \
  : "=&v"(A[0]), "=&v"(A[1]), "=&v"(A[2]), "=&v"(A[3]) \
  : "v"(P) : "memory")

__device__ inline int frag_ok(const f32x4 v){
  uint4 u = __builtin_bit_cast(uint4, v);
  return (u.x != 0xFFFFFFFFu) & (u.y != 0xFFFFFFFFu) &
         (u.z != 0xFFFFFFFFu) & (u.w != 0xFFFFFFFFu);
}

// poll 8 fragments with low-traffic canary retries
__device__ inline void poll8(f32x4* Af, const u16* A){
  G_LOAD8(Af, A);
  int ok = 1;
  #pragma unroll
  for (int i = 0; i < 8; i++) ok &= frag_ok(Af[i]);
  if (__all(ok)) return;
  int r = 0;
  for (;;){
    u32 c = g_canary((const u32*)(A + (r & 7)*32));
    r++;
    if (!__all((int)(c != 0xFFFFFFFFu))) continue;
    G_LOAD8(Af, A);
    ok = 1;
    #pragma unroll
    for (int i = 0; i < 8; i++) ok &= frag_ok(Af[i]);
    if (__all(ok)) return;
  }
}

__global__ void k_bias(const float* __restrict__ a0, const float* __restrict__ a1,
                       const float* __restrict__ a2, const float* __restrict__ a3,
                       float* __restrict__ b0, float* __restrict__ b1,
                       unsigned long long* __restrict__ h1z){
  int i = blockIdx.x*256 + threadIdx.x;
  if (i < 8192){ b0[i] = a0[i] + a1[i]; b1[i] = a2[i] + a3[i]; h1z[i] = 0ull; }
}

__global__ void k_embed(const int* __restrict__ inputs, const float* __restrict__ emb,
                        u16* __restrict__ X){
  int row = blockIdx.x;                 // t*16 + b
  int t = row >> 4, b = row & 15;
  int tok = (t == 0) ? 1 : inputs[b*TT + t];   // BOS=1 at t=0
  const float4* src = (const float4*)(emb + (size_t)tok*HH);
  float4 v = src[threadIdx.x];
  ushort4 o = make_ushort4(f2b(v.x), f2b(v.y), f2b(v.z), f2b(v.w));
  ((ushort4*)X)[(size_t)row*256 + threadIdx.x] = o;
}

// pack W[n][k] fp32 -> fragment-major bf16, frag elem j <-> k = ks*32+(l>>4)*8+j
__global__ void k_pack(const float* __restrict__ sA, const float* __restrict__ sB,
                       int KA, int KB, u16* __restrict__ dst){
  int K = KA + KB, KS = K >> 5;
  long idx = (long)blockIdx.x*256 + threadIdx.x;
  long total = 2L*64*4*KS*64;
  if (idx >= total) return;
  int l = (int)(idx & 63);
  long r = idx >> 6;
  int ks = (int)(r % KS); r /= KS;
  int g  = (int)(r & 3);  r >>= 2;
  int jb = (int)(r & 63); r >>= 6;
  int cell = (int)r;
  int n  = g*1024 + jb*16 + (l & 15);
  int k0 = ks*32 + ((l >> 4) << 3);
  const float* s; int kl;
  if (k0 < KA){ s = sA + (long)(cell*4096 + n)*KA; kl = k0; }
  else        { s = sB + (long)(cell*4096 + n)*KB; kl = k0 - KA; }
  float4 f0 = *(const float4*)(s + kl);
  float4 f1 = *(const float4*)(s + kl + 4);
  union { u16 v[8]; int4 q; } o;
  o.v[0]=f2b(f0.x); o.v[1]=f2b(f0.y); o.v[2]=f2b(f0.z); o.v[3]=f2b(f0.w);
  o.v[4]=f2b(f1.x); o.v[5]=f2b(f1.y); o.v[6]=f2b(f1.z); o.v[7]=f2b(f1.w);
  long d = ((((long)cell*64 + jb)*4 + g)*KS + ks)*64 + l;
  ((int4*)dst)[d] = o.q;
}

__global__ __launch_bounds__(512, 2)
void k_fused(const u16* __restrict__ Wih0p, const u16* __restrict__ Whh0p,
             const u16* __restrict__ W1p, const float* __restrict__ b0,
             const float* __restrict__ b1, const u16* __restrict__ Xb,
             u16* h0_all, u16* h1r, float* __restrict__ out)
{
  extern __shared__ char smem[];
  float*  gl   = (float*)smem;                  // [8 waves][4 gates][16*17] padded
  f32x4*  wlds = (f32x4*)(smem + 34816);        // l1 h1-weights [4][24][64] frags

  const int tid  = threadIdx.x;
  const int wv   = tid >> 6, l = tid & 63;
  const int rowA = l & 15;
  const int kq8  = (l >> 4) * 8;
  const int layer = blockIdx.x >> 7;
  const int bid   = blockIdx.x & 127;
  const int cell  = bid >> 6, jb = bid & 63;
  const int b_ = tid >> 4, j = tid & 15;        // epilogue ownership (tid<256)
  const int ep = b_*17 + j;                     // padded epilogue read offset

  float bias[4];
  {
    const float* bb = (layer == 0 ? b0 : b1) + cell*4096 + jb*16 + rowA;
    #pragma unroll
    for (int g = 0; g < 4; g++) bias[g] = (wv == 0) ? bb[g*1024] : 0.f;
  }
  float creg = 0.f;

  if (layer == 0){
    // waves 0-3: ih (X) ks (wv&3)*8..+7 ; waves 4-7: hh (h0) ks (wv&3)*8..+7
    f32x4 w[4][8];
    {
      const f32x4* src = (const f32x4*)(wv < 4 ? Wih0p : Whh0p)
                       + ((long)(cell*64 + jb)*4)*32*64 + l;
      #pragma unroll
      for (int g = 0; g < 4; g++)
        #pragma unroll
        for (int i = 0; i < 8; i++)
          w[g][i] = src[((long)g*32 + (wv & 3)*8 + i)*64];
    }
    #pragma unroll
    for (int g = 0; g < 4; g++)
      #pragma unroll
      for (int i = 0; i < 8; i++) asm volatile("" : "+v"(w[g][i]));
    __syncthreads();

    u32* hdst = (u32*)h0_all;
    const int ko = (wv & 3)*256;

    for (int t = 0; t < TT; t++){
      f32x4 acc[4];
      #pragma unroll
      for (int g = 0; g < 4; g++) acc[g] = (f32x4){bias[g],bias[g],bias[g],bias[g]};
      if (wv < 4){
        const u16* A = Xb + ((long)t*16 + rowA)*1024 + ko + kq8;
        f32x4 Af[8];
        #pragma unroll
        for (int i = 0; i < 8; i++) Af[i] = *(const f32x4*)(A + i*32);
        #pragma unroll
        for (int i = 0; i < 8; i++)
          #pragma unroll
          for (int g = 0; g < 4; g++)
            acc[g] = MFMA(__builtin_bit_cast(bf16x8, Af[i]),
                          __builtin_bit_cast(bf16x8, w[g][i]), acc[g], 0, 0, 0);
      } else if (t > 0){
        const u16* A = h0_all + (((long)(t-1)*2 + cell)*16 + rowA)*1024 + ko + kq8;
        f32x4 Af[8];
        poll8(Af, A);                           // sentinel poll, canary retries
        #pragma unroll
        for (int i = 0; i < 8; i++)
          #pragma unroll
          for (int g = 0; g < 4; g++)
            acc[g] = MFMA(__builtin_bit_cast(bf16x8, Af[i]),
                          __builtin_bit_cast(bf16x8, w[g][i]), acc[g], 0, 0, 0);
      }
      {
        int r0 = (l >> 4)*4, cj = l & 15;
        #pragma unroll
        for (int g = 0; g < 4; g++)
          #pragma unroll
          for (int i2 = 0; i2 < 4; i2++)
            gl[wv*1088 + g*272 + (r0+i2)*17 + cj] = acc[g][i2];
      }
      __syncthreads();                          // B: all 8 partials in gl
      if (tid < 256){
        float s0=0.f, s1=0.f, s2=0.f, s3=0.f;
        #pragma unroll
        for (int wq = 0; wq < 8; wq++){
          s0 += gl[wq*1088 + ep];
          s1 += gl[wq*1088 + 272 + ep];
          s2 += gl[wq*1088 + 544 + ep];
          s3 += gl[wq*1088 + 816 + ep];
        }
        float c2 = sigm(s1)*creg + sigm(s0)*tanh_(s2);
        float h2 = sigm(s3)*tanh_(c2);
        creg = c2;
        u32 lo = f2b(h2), hi = __shfl_down(lo, 1);
        if (!(tid & 1)){
          long idx = ((((long)t*2 + cell)*16 + b_)*1024 + jb*16 + j) >> 1;
          g_store32(hdst + idx, lo | (hi << 16));   // fire-and-forget
        }
      }
      __syncthreads();                          // C: gl safe to reuse
    }
  } else {
    // l1: per wave: h0 ks wv*8..+7 (regs), h1 ks 64+wv*4 (1 frag reg + 3 LDS)
    f32x4 wh0[4][8];
    f32x4 wh1[4];
    {
      const f32x4* src = (const f32x4*)W1p + ((long)(cell*64 + jb)*4)*96*64 + l;
      #pragma unroll
      for (int g = 0; g < 4; g++){
        #pragma unroll
        for (int i = 0; i < 8; i++)
          wh0[g][i] = src[((long)g*96 + wv*8 + i)*64];
        wh1[g] = src[((long)g*96 + 64 + wv*4)*64];
      }
      const f32x4* wb = (const f32x4*)W1p + ((long)(cell*64 + jb)*4)*96*64;
      for (int i = tid; i < 6144; i += 512){
        int g = i / 1536, r = (i % 1536) >> 6, ll = i & 63;
        int ksl = 64 + (r/3)*4 + (r%3) + 1;
        wlds[i] = wb[((long)g*96 + ksl)*64 + ll];
      }
    }
    #pragma unroll
    for (int g = 0; g < 4; g++){
      #pragma unroll
      for (int i = 0; i < 8; i++) asm volatile("" : "+v"(wh0[g][i]));
      asm volatile("" : "+v"(wh1[g]));
    }
    __syncthreads();

    u32* h1d = (u32*)h1r;

    for (int t = 0; t < TT; t++){
      // early-issue h1(t-1) attempt (hides under h0-part compute)
      f32x4 Bf[4];
      const u16* Ah = h1r + (((long)((t+3)&3)*2 + cell)*16 + rowA)*1024
                    + wv*128 + kq8;
      G_LOAD4_ISSUE(Bf, Ah);
      // reset slot (t+1)&3 (holds h1(t-3); provably unread). Drained by this
      // wave's h0-poll vmcnt(0) below, before epilogue data stores issue.
      if (tid < 256 && !(tid & 1)){
        long idx = ((((long)((t+1)&3)*2 + cell)*16 + b_)*1024 + jb*16 + j) >> 1;
        g_store32(h1d + idx, 0xFFFFFFFFu);
      }
      // h0f/h0b(t) sentinel poll on own fragments
      f32x4 acc[4];
      #pragma unroll
      for (int g = 0; g < 4; g++) acc[g] = (f32x4){bias[g],bias[g],bias[g],bias[g]};
      {
        const u16* A = h0_all + ((long)t*32 + (wv>>2)*16 + rowA)*1024
                     + (wv & 3)*256 + kq8;
        f32x4 Af[8];
        poll8(Af, A);
        #pragma unroll
        for (int i = 0; i < 8; i++)
          #pragma unroll
          for (int g = 0; g < 4; g++)
            acc[g] = MFMA(__builtin_bit_cast(bf16x8, Af[i]),
                          __builtin_bit_cast(bf16x8, wh0[g][i]), acc[g], 0, 0, 0);
      }
      // h1(t-1): verify early data; canary-retry on sentinel
      G_WAIT4(Bf);
      {
        int ok = 1;
        #pragma unroll
        for (int i = 0; i < 4; i++) ok &= frag_ok(Bf[i]);
        if (!__all(ok)){
          int r = 0;
          for (;;){
            u32 c = g_canary((const u32*)(Ah + (r & 3)*32));
            r++;
            if (!__all((int)(c != 0xFFFFFFFFu))) continue;
            G_LOAD4W(Bf, Ah);
            ok = 1;
            #pragma unroll
            for (int i = 0; i < 4; i++) ok &= frag_ok(Bf[i]);
            if (__all(ok)) break;
          }
        }
      }
      #pragma unroll
      for (int i = 0; i < 4; i++)
        #pragma unroll
        for (int g = 0; g < 4; g++){
          f32x4 bw = (i == 0) ? wh1[g] : wlds[(g*24 + wv*3 + (i-1))*64 + l];
          acc[g] = MFMA(__builtin_bit_cast(bf16x8, Bf[i]),
                        __builtin_bit_cast(bf16x8, bw), acc[g], 0, 0, 0);
        }
      {
        int r0 = (l >> 4)*4, cj = l & 15;
        #pragma unroll
        for (int g = 0; g < 4; g++)
          #pragma unroll
          for (int i2 = 0; i2 < 4; i2++)
            gl[wv*1088 + g*272 + (r0+i2)*17 + cj] = acc[g][i2];
      }
      __syncthreads();                          // B: partials in gl
      if (tid < 256){
        float s0=0.f, s1=0.f, s2=0.f, s3=0.f;
        #pragma unroll
        for (int wq = 0; wq < 8; wq++){
          s0 += gl[wq*1088 + ep];
          s1 += gl[wq*1088 + 272 + ep];
          s2 += gl[wq*1088 + 544 + ep];
          s3 += gl[wq*1088 + 816 + ep];
        }
        float c2 = sigm(s1)*creg + sigm(s0)*tanh_(s2);
        float h2 = sigm(s3)*tanh_(c2);
        creg = c2;
        out[((long)b_*TT + t)*2048 + cell*1024 + jb*16 + j] = h2;
        u32 lo = f2b(h2), hi = __shfl_down(lo, 1);
        if (!(tid & 1)){
          long idx = ((((long)(t & 3)*2 + cell)*16 + b_)*1024 + jb*16 + j) >> 1;
          g_store32(h1d + idx, lo | (hi << 16));   // fire-and-forget
        }
      }
      __syncthreads();                          // C: gl safe to reuse
    }
  }
}

extern "C" void kernel_launch(void* const* d_in, const int* in_sizes, int n_in,
                              void* d_out, int out_size, void* d_ws, size_t ws_size,
                              hipStream_t stream){
  const int*   inputs = (const int*)d_in[0];
  const float* emb    = (const float*)d_in[1];
  const float* wih0   = (const float*)d_in[2];
  const float* whh0   = (const float*)d_in[3];
  const float* bih0   = (const float*)d_in[4];
  const float* bhh0   = (const float*)d_in[5];
  const float* wih1   = (const float*)d_in[6];
  const float* whh1   = (const float*)d_in[7];
  const float* bih1   = (const float*)d_in[8];
  const float* bhh1   = (const float*)d_in[9];
  float* out = (float*)d_out;
  char* ws = (char*)d_ws;

  float* b0    = (float*)(ws + OFS_B0);
  float* b1    = (float*)(ws + OFS_B1);
  u16*   Xb    = (u16*)(ws + OFS_X);
  u16*   Wih0p = (u16*)(ws + OFS_WIH0);
  u16*   Whh0p = (u16*)(ws + OFS_WHH0);
  u16*   W1p   = (u16*)(ws + OFS_W1);
  u16*   h0a   = (u16*)(ws + OFS_H0);
  u16*   h1r   = (u16*)(ws + OFS_H1);
  unsigned long long* h1z = (unsigned long long*)(ws + OFS_H1 + 196608ul);

  // arm sentinels: full h0 history + h1 ring slots 0-2 (slot 3 zeroed by k_bias)
  hipMemsetAsync(ws + OFS_H0, 0xFF, 33554432ul, stream);
  hipMemsetAsync(ws + OFS_H1, 0xFF, 196608ul, stream);
  k_bias <<<32,   256, 0, stream>>>(bih0, bhh0, bih1, bhh1, b0, b1, h1z);
  k_embed<<<8192, 256, 0, stream>>>(inputs, emb, Xb);
  k_pack <<<4096, 256, 0, stream>>>(wih0, (const float*)0, 1024, 0, Wih0p);
  k_pack <<<4096, 256, 0, stream>>>(whh0, (const float*)0, 1024, 0, Whh0p);
  k_pack <<<12288,256, 0, stream>>>(wih1, whh1, 2048, 1024, W1p);

  const int smem_bytes = 34816 + 98304;   // padded gl 34KB + l1 h1-weights 96KB
  hipFuncSetAttribute(reinterpret_cast<const void*>(&k_fused),
                      hipFuncAttributeMaxDynamicSharedMemorySize, smem_bytes);
  k_fused<<<256, 512, smem_bytes, stream>>>(Wih0p, Whh0p, W1p, b0, b1, Xb,
                                            h0a, h1r, out);
}

// Round 12
// 3402.481 us; speedup vs baseline: 1.0706x; 1.0706x over previous
//
#include <hip/hip_runtime.h>
#include <hip/hip_bf16.h>
#include <stdint.h>

// Bidirectional 2-layer LSTM decoder: B=16, T=512, E=H=1024.
// Round-12 = R9 (3043us, passed) + hazard-free speculation:
//  - RAW barriers (lgkmcnt(0)+s_barrier, no vmcnt drain) in both t-loops.
//  - l0 hh waves: during step t's epilogue window (B..C), sleep ~770cy then
//    issue 8x global_load_lds (sc0|sc1) staging h0(t) into private LDS.
//    global_load_lds has NO dest VGPRs -> no async-register hazard (R11's NaN
//    root cause), and plain vmcnt(0) waits are spill-robust. At top of t+1:
//    vmcnt(0), LDS read-back, sentinel check; fall back to R9's serial poll8
//    on miss. h0 is write-once + launch-deterministic, so any stale cached
//    line is sentinel or correct -> fallback is always sound.
//  - l1: raw barriers only; h1 early-issue/verify exactly as R9.

#define TT 512
#define HH 1024

typedef __bf16 bf16x8 __attribute__((ext_vector_type(8)));
typedef float f32x4 __attribute__((ext_vector_type(4)));
typedef unsigned int u32;
typedef unsigned short u16;

#define MFMA __builtin_amdgcn_mfma_f32_16x16x32_bf16
#define RAW_BAR() asm volatile("s_waitcnt lgkmcnt(0)\n\ts_barrier" ::: "memory")

// ---- workspace layout (bytes) ----
#define OFS_B0    4096ul         // [2][4096] f32
#define OFS_B1    36864ul        // [2][4096] f32
#define OFS_X     69632ul        // [8192][1024] bf16
#define OFS_WIH0  16846848ul     // packed [2][64][4][32][64][8] bf16
#define OFS_WHH0  33624064ul     // same shape
#define OFS_W1    50401280ul     // packed [2][64][4][96][64][8] bf16 (h0 64ks | h1 32ks)
#define OFS_H0    100732928ul    // [512][2][16][1024] bf16 (write-once, sentinel-armed)
#define OFS_H1    134287360ul    // [4][2][16][1024] bf16 ring (sentinel protocol)
// end ~134.55 MB

__device__ inline u16 f2b(float f){
  union { float f; u32 u; } x{f};
  return (u16)((x.u + 0x7FFFu + ((x.u >> 16) & 1u)) >> 16);
}
__device__ inline float sigm(float x){ return 1.f/(1.f + __expf(-x)); }
__device__ inline float tanh_(float x){ return 2.f*sigm(2.f*x) - 1.f; }

__device__ inline void g_store32(u32* p, u32 v){
  asm volatile("global_store_dword %0, %1, off sc0 sc1" :: "v"(p), "v"(v) : "memory");
}

// async global->LDS stage, 16B/lane, MALL-coherent (sc0|sc1 = 0x11)
__device__ inline void async_ld16(const u16* g, char* l){
  __builtin_amdgcn_global_load_lds(
      (const __attribute__((address_space(1))) void*)g,
      (__attribute__((address_space(3))) void*)l, 16, 0, 0x11);
}

// 8x16B coherent loads + single wait (serial poll body / fallback)
#define G_LOAD8(A, P) asm volatile( \
  "global_load_dwordx4 %0, %8, off sc0 sc1\n\t" \
  "global_load_dwordx4 %1, %8, off offset:64 sc0 sc1\n\t" \
  "global_load_dwordx4 %2, %8, off offset:128 sc0 sc1\n\t" \
  "global_load_dwordx4 %3, %8, off offset:192 sc0 sc1\n\t" \
  "global_load_dwordx4 %4, %8, off offset:256 sc0 sc1\n\t" \
  "global_load_dwordx4 %5, %8, off offset:320 sc0 sc1\n\t" \
  "global_load_dwordx4 %6, %8, off offset:384 sc0 sc1\n\t" \
  "global_load_dwordx4 %7, %8, off offset:448 sc0 sc1\n\t" \
  "s_waitcnt vmcnt(0)" \
  : "=&v"(A[0]), "=&v"(A[1]), "=&v"(A[2]), "=&v"(A[3]), \
    "=&v"(A[4]), "=&v"(A[5]), "=&v"(A[6]), "=&v"(A[7]) \
  : "v"(P) : "memory")

// issue 4x16B sc1 loads WITHOUT waiting (l1 h1 early-issue, proven R8-R10)
#define G_LOAD4_ISSUE(A, P) asm volatile( \
  "global_load_dwordx4 %0, %4, off sc0 sc1\n\t" \
  "global_load_dwordx4 %1, %4, off offset:64 sc0 sc1\n\t" \
  "global_load_dwordx4 %2, %4, off offset:128 sc0 sc1\n\t" \
  "global_load_dwordx4 %3, %4, off offset:192 sc0 sc1" \
  : "=&v"(A[0]), "=&v"(A[1]), "=&v"(A[2]), "=&v"(A[3]) \
  : "v"(P) : "memory")
#define G_WAIT4(A) asm volatile("s_waitcnt vmcnt(0)" \
  : "+v"(A[0]), "+v"(A[1]), "+v"(A[2]), "+v"(A[3]) :: "memory")
#define G_LOAD4W(A, P) asm volatile( \
  "global_load_dwordx4 %0, %4, off sc0 sc1\n\t" \
  "global_load_dwordx4 %1, %4, off offset:64 sc0 sc1\n\t" \
  "global_load_dwordx4 %2, %4, off offset:128 sc0 sc1\n\t" \
  "global_load_dwordx4 %3, %4, off offset:192 sc0 sc1\n\t" \
  "s_waitcnt vmcnt(0)" \
  : "=&v"(A[0]), "=&v"(A[1]), "=&v"(A[2]), "=&v"(A[3]) \
  : "v"(P) : "memory")

__device__ inline int frag_ok(const f32x4 v){
  uint4 u = __builtin_bit_cast(uint4, v);
  return (u.x != 0xFFFFFFFFu) & (u.y != 0xFFFFFFFFu) &
         (u.z != 0xFFFFFFFFu) & (u.w != 0xFFFFFFFFu);
}

// serial poll (fallback, proven R9)
__device__ inline void poll8(f32x4* Af, const u16* A){
  for (;;){
    G_LOAD8(Af, A);
    int ok = 1;
    #pragma unroll
    for (int i = 0; i < 8; i++) ok &= frag_ok(Af[i]);
    if (__all(ok)) return;
  }
}

__global__ void k_bias(const float* __restrict__ a0, const float* __restrict__ a1,
                       const float* __restrict__ a2, const float* __restrict__ a3,
                       float* __restrict__ b0, float* __restrict__ b1,
                       unsigned long long* __restrict__ h1z){
  int i = blockIdx.x*256 + threadIdx.x;
  if (i < 8192){ b0[i] = a0[i] + a1[i]; b1[i] = a2[i] + a3[i]; h1z[i] = 0ull; }
}

__global__ void k_embed(const int* __restrict__ inputs, const float* __restrict__ emb,
                        u16* __restrict__ X){
  int row = blockIdx.x;                 // t*16 + b
  int t = row >> 4, b = row & 15;
  int tok = (t == 0) ? 1 : inputs[b*TT + t];   // BOS=1 at t=0
  const float4* src = (const float4*)(emb + (size_t)tok*HH);
  float4 v = src[threadIdx.x];
  ushort4 o = make_ushort4(f2b(v.x), f2b(v.y), f2b(v.z), f2b(v.w));
  ((ushort4*)X)[(size_t)row*256 + threadIdx.x] = o;
}

// pack W[n][k] fp32 -> fragment-major bf16, frag elem j <-> k = ks*32+(l>>4)*8+j
__global__ void k_pack(const float* __restrict__ sA, const float* __restrict__ sB,
                       int KA, int KB, u16* __restrict__ dst){
  int K = KA + KB, KS = K >> 5;
  long idx = (long)blockIdx.x*256 + threadIdx.x;
  long total = 2L*64*4*KS*64;
  if (idx >= total) return;
  int l = (int)(idx & 63);
  long r = idx >> 6;
  int ks = (int)(r % KS); r /= KS;
  int g  = (int)(r & 3);  r >>= 2;
  int jb = (int)(r & 63); r >>= 6;
  int cell = (int)r;
  int n  = g*1024 + jb*16 + (l & 15);
  int k0 = ks*32 + ((l >> 4) << 3);
  const float* s; int kl;
  if (k0 < KA){ s = sA + (long)(cell*4096 + n)*KA; kl = k0; }
  else        { s = sB + (long)(cell*4096 + n)*KB; kl = k0 - KA; }
  float4 f0 = *(const float4*)(s + kl);
  float4 f1 = *(const float4*)(s + kl + 4);
  union { u16 v[8]; int4 q; } o;
  o.v[0]=f2b(f0.x); o.v[1]=f2b(f0.y); o.v[2]=f2b(f0.z); o.v[3]=f2b(f0.w);
  o.v[4]=f2b(f1.x); o.v[5]=f2b(f1.y); o.v[6]=f2b(f1.z); o.v[7]=f2b(f1.w);
  long d = ((((long)cell*64 + jb)*4 + g)*KS + ks)*64 + l;
  ((int4*)dst)[d] = o.q;
}

__global__ __launch_bounds__(512, 2)
void k_fused(const u16* __restrict__ Wih0p, const u16* __restrict__ Whh0p,
             const u16* __restrict__ W1p, const float* __restrict__ b0,
             const float* __restrict__ b1, const u16* __restrict__ Xb,
             u16* h0_all, u16* h1r, float* __restrict__ out)
{
  extern __shared__ char smem[];
  float*  gl   = (float*)smem;                  // [8 waves][4 gates][256] partials
  f32x4*  wlds = (f32x4*)(smem + 32768);        // l1 h1-weights [4][24][64] frags
  // l0 hh stage region: smem + 32768 + (wv-4)*8192, 8KB per hh wave

  const int tid  = threadIdx.x;
  const int wv   = tid >> 6, l = tid & 63;
  const int rowA = l & 15;
  const int kq8  = (l >> 4) * 8;
  const int layer = blockIdx.x >> 7;
  const int bid   = blockIdx.x & 127;
  const int cell  = bid >> 6, jb = bid & 63;
  const int b_ = tid >> 4, j = tid & 15;        // epilogue ownership (tid<256)

  float bias[4];
  {
    const float* bb = (layer == 0 ? b0 : b1) + cell*4096 + jb*16 + rowA;
    #pragma unroll
    for (int g = 0; g < 4; g++) bias[g] = (wv == 0) ? bb[g*1024] : 0.f;
  }
  float creg = 0.f;

  if (layer == 0){
    // waves 0-3: ih (X) ks (wv&3)*8..+7 ; waves 4-7: hh (h0) ks (wv&3)*8..+7
    f32x4 w[4][8];
    {
      const f32x4* src = (const f32x4*)(wv < 4 ? Wih0p : Whh0p)
                       + ((long)(cell*64 + jb)*4)*32*64 + l;
      #pragma unroll
      for (int g = 0; g < 4; g++)
        #pragma unroll
        for (int i = 0; i < 8; i++)
          w[g][i] = src[((long)g*32 + (wv & 3)*8 + i)*64];
    }
    #pragma unroll
    for (int g = 0; g < 4; g++)
      #pragma unroll
      for (int i = 0; i < 8; i++) asm volatile("" : "+v"(w[g][i]));
    __syncthreads();

    u32* hdst = (u32*)h0_all;
    const int ko = (wv & 3)*256;
    const f32x4* sv = (const f32x4*)(smem + 32768 + (wv & 3)*8192);
    char* sb = smem + 32768 + (wv & 3)*8192;

    for (int t = 0; t < TT; t++){
      f32x4 acc[4];
      #pragma unroll
      for (int g = 0; g < 4; g++) acc[g] = (f32x4){bias[g],bias[g],bias[g],bias[g]};
      if (wv < 4){
        const u16* A = Xb + ((long)t*16 + rowA)*1024 + ko + kq8;
        f32x4 Af[8];
        #pragma unroll
        for (int i = 0; i < 8; i++) Af[i] = *(const f32x4*)(A + i*32);
        #pragma unroll
        for (int i = 0; i < 8; i++)
          #pragma unroll
          for (int g = 0; g < 4; g++)
            acc[g] = MFMA(__builtin_bit_cast(bf16x8, Af[i]),
                          __builtin_bit_cast(bf16x8, w[g][i]), acc[g], 0, 0, 0);
      } else if (t > 0){
        // check speculative stage (issued in step t-1's epilogue window)
        const u16* A = h0_all + (((long)(t-1)*2 + cell)*16 + rowA)*1024 + ko + kq8;
        f32x4 Af[8];
        asm volatile("s_waitcnt vmcnt(0)" ::: "memory");   // stage landed
        #pragma unroll
        for (int i = 0; i < 8; i++) Af[i] = sv[i*64 + l];
        int ok = 1;
        #pragma unroll
        for (int i = 0; i < 8; i++) ok &= frag_ok(Af[i]);
        if (!__all(ok)) poll8(Af, A);                      // fallback (R9 path)
        #pragma unroll
        for (int i = 0; i < 8; i++)
          #pragma unroll
          for (int g = 0; g < 4; g++)
            acc[g] = MFMA(__builtin_bit_cast(bf16x8, Af[i]),
                          __builtin_bit_cast(bf16x8, w[g][i]), acc[g], 0, 0, 0);
      }
      {
        int r0 = (l >> 4)*4, cj = l & 15;
        #pragma unroll
        for (int g = 0; g < 4; g++)
          #pragma unroll
          for (int i2 = 0; i2 < 4; i2++)
            gl[wv*1024 + g*256 + (r0+i2)*16 + cj] = acc[g][i2];
      }
      RAW_BAR();                                // B: all 8 partials in gl
      if (tid < 256){
        float s0=0.f, s1=0.f, s2=0.f, s3=0.f;
        #pragma unroll
        for (int wq = 0; wq < 8; wq++){
          s0 += gl[wq*1024 + tid];
          s1 += gl[wq*1024 + 256 + tid];
          s2 += gl[wq*1024 + 512 + tid];
          s3 += gl[wq*1024 + 768 + tid];
        }
        float c2 = sigm(s1)*creg + sigm(s0)*tanh_(s2);
        float h2 = sigm(s3)*tanh_(c2);
        creg = c2;
        u32 lo = f2b(h2), hi = __shfl_down(lo, 1);
        if (!(tid & 1)){
          long idx = ((((long)t*2 + cell)*16 + b_)*1024 + jb*16 + j) >> 1;
          g_store32(hdst + idx, lo | (hi << 16));   // fire-and-forget
        }
      } else if (t < TT-1){
        // speculative stage of h0(t) for next step (async, no dest regs)
        __builtin_amdgcn_s_sleep(12);               // let remote epilogues store
        const u16* An = h0_all + (((long)t*2 + cell)*16 + rowA)*1024 + ko + kq8;
        #pragma unroll
        for (int i = 0; i < 8; i++) async_ld16(An + i*32, sb + i*1024);
      }
      RAW_BAR();                                // C: gl safe to reuse
    }
  } else {
    // l1: per wave: h0 ks wv*8..+7 (regs), h1 ks 64+wv*4 (1 frag reg + 3 LDS)
    f32x4 wh0[4][8];
    f32x4 wh1[4];
    {
      const f32x4* src = (const f32x4*)W1p + ((long)(cell*64 + jb)*4)*96*64 + l;
      #pragma unroll
      for (int g = 0; g < 4; g++){
        #pragma unroll
        for (int i = 0; i < 8; i++)
          wh0[g][i] = src[((long)g*96 + wv*8 + i)*64];
        wh1[g] = src[((long)g*96 + 64 + wv*4)*64];
      }
      const f32x4* wb = (const f32x4*)W1p + ((long)(cell*64 + jb)*4)*96*64;
      for (int i = tid; i < 6144; i += 512){
        int g = i / 1536, r = (i % 1536) >> 6, ll = i & 63;
        int ksl = 64 + (r/3)*4 + (r%3) + 1;
        wlds[i] = wb[((long)g*96 + ksl)*64 + ll];
      }
    }
    #pragma unroll
    for (int g = 0; g < 4; g++){
      #pragma unroll
      for (int i = 0; i < 8; i++) asm volatile("" : "+v"(wh0[g][i]));
      asm volatile("" : "+v"(wh1[g]));
    }
    __syncthreads();

    u32* h1d = (u32*)h1r;

    for (int t = 0; t < TT; t++){
      // early-issue h1(t-1) attempt (hides under h0-part compute)
      f32x4 Bf[4];
      const u16* Ah = h1r + (((long)((t+3)&3)*2 + cell)*16 + rowA)*1024
                    + wv*128 + kq8;
      G_LOAD4_ISSUE(Bf, Ah);
      // reset slot (t+1)&3 (holds h1(t-3); provably unread). Drained by this
      // wave's own later vmcnt(0)s before that slot's next write.
      if (tid < 256 && !(tid & 1)){
        long idx = ((((long)((t+1)&3)*2 + cell)*16 + b_)*1024 + jb*16 + j) >> 1;
        g_store32(h1d + idx, 0xFFFFFFFFu);
      }
      // h0f/h0b(t) sentinel poll on own fragments
      f32x4 acc[4];
      #pragma unroll
      for (int g = 0; g < 4; g++) acc[g] = (f32x4){bias[g],bias[g],bias[g],bias[g]};
      {
        const u16* A = h0_all + ((long)t*32 + (wv>>2)*16 + rowA)*1024
                     + (wv & 3)*256 + kq8;
        f32x4 Af[8];
        poll8(Af, A);
        #pragma unroll
        for (int i = 0; i < 8; i++)
          #pragma unroll
          for (int g = 0; g < 4; g++)
            acc[g] = MFMA(__builtin_bit_cast(bf16x8, Af[i]),
                          __builtin_bit_cast(bf16x8, wh0[g][i]), acc[g], 0, 0, 0);
      }
      // h1(t-1): verify early data; serial retry on sentinel
      G_WAIT4(Bf);
      {
        int ok = 1;
        #pragma unroll
        for (int i = 0; i < 4; i++) ok &= frag_ok(Bf[i]);
        while (!__all(ok)){
          G_LOAD4W(Bf, Ah);
          ok = 1;
          #pragma unroll
          for (int i = 0; i < 4; i++) ok &= frag_ok(Bf[i]);
        }
      }
      #pragma unroll
      for (int i = 0; i < 4; i++)
        #pragma unroll
        for (int g = 0; g < 4; g++){
          f32x4 bw = (i == 0) ? wh1[g] : wlds[(g*24 + wv*3 + (i-1))*64 + l];
          acc[g] = MFMA(__builtin_bit_cast(bf16x8, Bf[i]),
                        __builtin_bit_cast(bf16x8, bw), acc[g], 0, 0, 0);
        }
      {
        int r0 = (l >> 4)*4, cj = l & 15;
        #pragma unroll
        for (int g = 0; g < 4; g++)
          #pragma unroll
          for (int i2 = 0; i2 < 4; i2++)
            gl[wv*1024 + g*256 + (r0+i2)*16 + cj] = acc[g][i2];
      }
      RAW_BAR();                                // B: partials in gl
      if (tid < 256){
        float s0=0.f, s1=0.f, s2=0.f, s3=0.f;
        #pragma unroll
        for (int wq = 0; wq < 8; wq++){
          s0 += gl[wq*1024 + tid];
          s1 += gl[wq*1024 + 256 + tid];
          s2 += gl[wq*1024 + 512 + tid];
          s3 += gl[wq*1024 + 768 + tid];
        }
        float c2 = sigm(s1)*creg + sigm(s0)*tanh_(s2);
        float h2 = sigm(s3)*tanh_(c2);
        creg = c2;
        out[((long)b_*TT + t)*2048 + cell*1024 + jb*16 + j] = h2;
        u32 lo = f2b(h2), hi = __shfl_down(lo, 1);
        if (!(tid & 1)){
          long idx = ((((long)(t & 3)*2 + cell)*16 + b_)*1024 + jb*16 + j) >> 1;
          g_store32(h1d + idx, lo | (hi << 16));   // fire-and-forget
        }
      }
      RAW_BAR();                                // C: gl safe to reuse
    }
  }
}

extern "C" void kernel_launch(void* const* d_in, const int* in_sizes, int n_in,
                              void* d_out, int out_size, void* d_ws, size_t ws_size,
                              hipStream_t stream){
  const int*   inputs = (const int*)d_in[0];
  const float* emb    = (const float*)d_in[1];
  const float* wih0   = (const float*)d_in[2];
  const float* whh0   = (const float*)d_in[3];
  const float* bih0   = (const float*)d_in[4];
  const float* bhh0   = (const float*)d_in[5];
  const float* wih1   = (const float*)d_in[6];
  const float* whh1   = (const float*)d_in[7];
  const float* bih1   = (const float*)d_in[8];
  const float* bhh1   = (const float*)d_in[9];
  float* out = (float*)d_out;
  char* ws = (char*)d_ws;

  float* b0    = (float*)(ws + OFS_B0);
  float* b1    = (float*)(ws + OFS_B1);
  u16*   Xb    = (u16*)(ws + OFS_X);
  u16*   Wih0p = (u16*)(ws + OFS_WIH0);
  u16*   Whh0p = (u16*)(ws + OFS_WHH0);
  u16*   W1p   = (u16*)(ws + OFS_W1);
  u16*   h0a   = (u16*)(ws + OFS_H0);
  u16*   h1r   = (u16*)(ws + OFS_H1);
  unsigned long long* h1z = (unsigned long long*)(ws + OFS_H1 + 196608ul);

  // arm sentinels: full h0 history + h1 ring slots 0-2 (slot 3 zeroed by k_bias)
  hipMemsetAsync(ws + OFS_H0, 0xFF, 33554432ul, stream);
  hipMemsetAsync(ws + OFS_H1, 0xFF, 196608ul, stream);
  k_bias <<<32,   256, 0, stream>>>(bih0, bhh0, bih1, bhh1, b0, b1, h1z);
  k_embed<<<8192, 256, 0, stream>>>(inputs, emb, Xb);
  k_pack <<<4096, 256, 0, stream>>>(wih0, (const float*)0, 1024, 0, Wih0p);
  k_pack <<<4096, 256, 0, stream>>>(whh0, (const float*)0, 1024, 0, Whh0p);
  k_pack <<<12288,256, 0, stream>>>(wih1, whh1, 2048, 1024, W1p);

  const int smem_bytes = 32768 + 98304;   // gl 32KB + (l0 stage 32KB | l1 wlds 96KB)
  hipFuncSetAttribute(reinterpret_cast<const void*>(&k_fused),
                      hipFuncAttributeMaxDynamicSharedMemorySize, smem_bytes);
  k_fused<<<256, 512, smem_bytes, stream>>>(Wih0p, Whh0p, W1p, b0, b1, Xb,
                                            h0a, h1r, out);
}

// Round 13
// 3056.064 us; speedup vs baseline: 1.1919x; 1.1134x over previous
//
#include <hip/hip_runtime.h>
#include <hip/hip_bf16.h>
#include <stdint.h>

// Bidirectional 2-layer LSTM decoder: B=16, T=512, E=H=1024.
// Round-13 = R9 (3043us, best) + compact-flag assisted polls:
//  - R9's data-poll re-streams ~6-8MB per retry round chip-wide (64 consumer
//    blocks x same 32KB region) -> MALL congested; R10's per-lane canary
//    failed because each lane still touched a distinct line.
//  - Now: producers ALSO store one progress dword per block (no drain, after
//    barrier C). Consumers do ONE optimistic data load; on sentinel-miss they
//    spin on ONE CACHELINE of flags (lane i = producer i's flag, 16 contiguous
//    dwords), then reload data; any residual sentinel -> R9 serial poll.
//    Flags are advisory; the data sentinel remains the correctness gate.
//  - Everything else identical to R9: h0 write-once + 0xFF sentinel with
//    fire-and-forget sc1 stores; h1 ring(4) sentinel with early-issue verify;
//    weights pinned (l0 32 frags/wave; l1 32 h0 + 4 h1 VGPR + 24 ks LDS).

#define TT 512
#define HH 1024

typedef __bf16 bf16x8 __attribute__((ext_vector_type(8)));
typedef float f32x4 __attribute__((ext_vector_type(4)));
typedef unsigned int u32;
typedef unsigned short u16;

#define MFMA __builtin_amdgcn_mfma_f32_16x16x32_bf16

// ---- workspace layout (bytes) ----
#define OFS_FLAGS 0ul            // [4][64] u32: [cell0 l0][cell1 l0][cell0 l1][cell1 l1]
#define OFS_B0    4096ul         // [2][4096] f32
#define OFS_B1    36864ul        // [2][4096] f32
#define OFS_X     69632ul        // [8192][1024] bf16
#define OFS_WIH0  16846848ul     // packed [2][64][4][32][64][8] bf16
#define OFS_WHH0  33624064ul     // same shape
#define OFS_W1    50401280ul     // packed [2][64][4][96][64][8] bf16 (h0 64ks | h1 32ks)
#define OFS_H0    100732928ul    // [512][2][16][1024] bf16 (write-once, sentinel-armed)
#define OFS_H1    134287360ul    // [4][2][16][1024] bf16 ring (sentinel protocol)
// end ~134.55 MB

__device__ inline u16 f2b(float f){
  union { float f; u32 u; } x{f};
  return (u16)((x.u + 0x7FFFu + ((x.u >> 16) & 1u)) >> 16);
}
__device__ inline float sigm(float x){ return 1.f/(1.f + __expf(-x)); }
__device__ inline float tanh_(float x){ return 2.f*sigm(2.f*x) - 1.f; }

__device__ inline void g_store32(u32* p, u32 v){
  asm volatile("global_store_dword %0, %1, off sc0 sc1" :: "v"(p), "v"(v) : "memory");
}
__device__ inline u32 g_ld32(const u32* p){
  u32 v;
  asm volatile("global_load_dword %0, %1, off sc0 sc1\n\t"
               "s_waitcnt vmcnt(0)" : "=&v"(v) : "v"(p) : "memory");
  return v;
}

// 8x16B coherent loads + single wait
#define G_LOAD8(A, P) asm volatile( \
  "global_load_dwordx4 %0, %8, off sc0 sc1\n\t" \
  "global_load_dwordx4 %1, %8, off offset:64 sc0 sc1\n\t" \
  "global_load_dwordx4 %2, %8, off offset:128 sc0 sc1\n\t" \
  "global_load_dwordx4 %3, %8, off offset:192 sc0 sc1\n\t" \
  "global_load_dwordx4 %4, %8, off offset:256 sc0 sc1\n\t" \
  "global_load_dwordx4 %5, %8, off offset:320 sc0 sc1\n\t" \
  "global_load_dwordx4 %6, %8, off offset:384 sc0 sc1\n\t" \
  "global_load_dwordx4 %7, %8, off offset:448 sc0 sc1\n\t" \
  "s_waitcnt vmcnt(0)" \
  : "=&v"(A[0]), "=&v"(A[1]), "=&v"(A[2]), "=&v"(A[3]), \
    "=&v"(A[4]), "=&v"(A[5]), "=&v"(A[6]), "=&v"(A[7]) \
  : "v"(P) : "memory")

// issue 4x16B sc1 loads WITHOUT waiting (l1 h1 early-issue)
#define G_LOAD4_ISSUE(A, P) asm volatile( \
  "global_load_dwordx4 %0, %4, off sc0 sc1\n\t" \
  "global_load_dwordx4 %1, %4, off offset:64 sc0 sc1\n\t" \
  "global_load_dwordx4 %2, %4, off offset:128 sc0 sc1\n\t" \
  "global_load_dwordx4 %3, %4, off offset:192 sc0 sc1" \
  : "=&v"(A[0]), "=&v"(A[1]), "=&v"(A[2]), "=&v"(A[3]) \
  : "v"(P) : "memory")
#define G_WAIT4(A) asm volatile("s_waitcnt vmcnt(0)" \
  : "+v"(A[0]), "+v"(A[1]), "+v"(A[2]), "+v"(A[3]) :: "memory")
#define G_LOAD4W(A, P) asm volatile( \
  "global_load_dwordx4 %0, %4, off sc0 sc1\n\t" \
  "global_load_dwordx4 %1, %4, off offset:64 sc0 sc1\n\t" \
  "global_load_dwordx4 %2, %4, off offset:128 sc0 sc1\n\t" \
  "global_load_dwordx4 %3, %4, off offset:192 sc0 sc1\n\t" \
  "s_waitcnt vmcnt(0)" \
  : "=&v"(A[0]), "=&v"(A[1]), "=&v"(A[2]), "=&v"(A[3]) \
  : "v"(P) : "memory")

__device__ inline int frag_ok(const f32x4 v){
  uint4 u = __builtin_bit_cast(uint4, v);
  return (u.x != 0xFFFFFFFFu) & (u.y != 0xFFFFFFFFu) &
         (u.z != 0xFFFFFFFFu) & (u.w != 0xFFFFFFFFu);
}

// low-traffic wait: lane li reads its producer's flag (1 cacheline per wave)
__device__ inline void flag_wait(const u32* f, int li, u32 tgt){
  for (;;){
    u32 c = g_ld32(f + li);
    if (__all((int)(c >= tgt))) return;
  }
}

// serial data poll (final fallback, proven R9)
__device__ inline void poll8(f32x4* Af, const u16* A){
  for (;;){
    G_LOAD8(Af, A);
    int ok = 1;
    #pragma unroll
    for (int i = 0; i < 8; i++) ok &= frag_ok(Af[i]);
    if (__all(ok)) return;
  }
}

__global__ void k_bias(const float* __restrict__ a0, const float* __restrict__ a1,
                       const float* __restrict__ a2, const float* __restrict__ a3,
                       float* __restrict__ b0, float* __restrict__ b1,
                       unsigned long long* __restrict__ h1z){
  int i = blockIdx.x*256 + threadIdx.x;
  if (i < 8192){ b0[i] = a0[i] + a1[i]; b1[i] = a2[i] + a3[i]; h1z[i] = 0ull; }
}

__global__ void k_embed(const int* __restrict__ inputs, const float* __restrict__ emb,
                        u16* __restrict__ X){
  int row = blockIdx.x;                 // t*16 + b
  int t = row >> 4, b = row & 15;
  int tok = (t == 0) ? 1 : inputs[b*TT + t];   // BOS=1 at t=0
  const float4* src = (const float4*)(emb + (size_t)tok*HH);
  float4 v = src[threadIdx.x];
  ushort4 o = make_ushort4(f2b(v.x), f2b(v.y), f2b(v.z), f2b(v.w));
  ((ushort4*)X)[(size_t)row*256 + threadIdx.x] = o;
}

// pack W[n][k] fp32 -> fragment-major bf16, frag elem j <-> k = ks*32+(l>>4)*8+j
__global__ void k_pack(const float* __restrict__ sA, const float* __restrict__ sB,
                       int KA, int KB, u16* __restrict__ dst){
  int K = KA + KB, KS = K >> 5;
  long idx = (long)blockIdx.x*256 + threadIdx.x;
  long total = 2L*64*4*KS*64;
  if (idx >= total) return;
  int l = (int)(idx & 63);
  long r = idx >> 6;
  int ks = (int)(r % KS); r /= KS;
  int g  = (int)(r & 3);  r >>= 2;
  int jb = (int)(r & 63); r >>= 6;
  int cell = (int)r;
  int n  = g*1024 + jb*16 + (l & 15);
  int k0 = ks*32 + ((l >> 4) << 3);
  const float* s; int kl;
  if (k0 < KA){ s = sA + (long)(cell*4096 + n)*KA; kl = k0; }
  else        { s = sB + (long)(cell*4096 + n)*KB; kl = k0 - KA; }
  float4 f0 = *(const float4*)(s + kl);
  float4 f1 = *(const float4*)(s + kl + 4);
  union { u16 v[8]; int4 q; } o;
  o.v[0]=f2b(f0.x); o.v[1]=f2b(f0.y); o.v[2]=f2b(f0.z); o.v[3]=f2b(f0.w);
  o.v[4]=f2b(f1.x); o.v[5]=f2b(f1.y); o.v[6]=f2b(f1.z); o.v[7]=f2b(f1.w);
  long d = ((((long)cell*64 + jb)*4 + g)*KS + ks)*64 + l;
  ((int4*)dst)[d] = o.q;
}

__global__ __launch_bounds__(512, 2)
void k_fused(const u16* __restrict__ Wih0p, const u16* __restrict__ Whh0p,
             const u16* __restrict__ W1p, const float* __restrict__ b0,
             const float* __restrict__ b1, const u16* __restrict__ Xb,
             u16* h0_all, u16* h1r, float* __restrict__ out, u32* flags)
{
  extern __shared__ char smem[];
  float*  gl   = (float*)smem;                  // [8 waves][4 gates][256] partials
  f32x4*  wlds = (f32x4*)(smem + 32768);        // l1 h1-weights [4][24][64] frags

  const int tid  = threadIdx.x;
  const int wv   = tid >> 6, l = tid & 63;
  const int rowA = l & 15;
  const int kq8  = (l >> 4) * 8;
  const int layer = blockIdx.x >> 7;
  const int bid   = blockIdx.x & 127;
  const int cell  = bid >> 6, jb = bid & 63;
  const int b_ = tid >> 4, j = tid & 15;        // epilogue ownership (tid<256)

  float bias[4];
  {
    const float* bb = (layer == 0 ? b0 : b1) + cell*4096 + jb*16 + rowA;
    #pragma unroll
    for (int g = 0; g < 4; g++) bias[g] = (wv == 0) ? bb[g*1024] : 0.f;
  }
  float creg = 0.f;

  if (layer == 0){
    // waves 0-3: ih (X) ks (wv&3)*8..+7 ; waves 4-7: hh (h0) ks (wv&3)*8..+7
    f32x4 w[4][8];
    {
      const f32x4* src = (const f32x4*)(wv < 4 ? Wih0p : Whh0p)
                       + ((long)(cell*64 + jb)*4)*32*64 + l;
      #pragma unroll
      for (int g = 0; g < 4; g++)
        #pragma unroll
        for (int i = 0; i < 8; i++)
          w[g][i] = src[((long)g*32 + (wv & 3)*8 + i)*64];
    }
    #pragma unroll
    for (int g = 0; g < 4; g++)
      #pragma unroll
      for (int i = 0; i < 8; i++) asm volatile("" : "+v"(w[g][i]));
    __syncthreads();

    u32* hdst = (u32*)h0_all;
    u32* myf  = flags + cell*64 + jb;
    const u32* flr = flags + cell*64 + (wv & 3)*16;   // my 16 producers
    const int ko = (wv & 3)*256;

    for (int t = 0; t < TT; t++){
      f32x4 acc[4];
      #pragma unroll
      for (int g = 0; g < 4; g++) acc[g] = (f32x4){bias[g],bias[g],bias[g],bias[g]};
      if (wv < 4){
        const u16* A = Xb + ((long)t*16 + rowA)*1024 + ko + kq8;
        f32x4 Af[8];
        #pragma unroll
        for (int i = 0; i < 8; i++) Af[i] = *(const f32x4*)(A + i*32);
        #pragma unroll
        for (int i = 0; i < 8; i++)
          #pragma unroll
          for (int g = 0; g < 4; g++)
            acc[g] = MFMA(__builtin_bit_cast(bf16x8, Af[i]),
                          __builtin_bit_cast(bf16x8, w[g][i]), acc[g], 0, 0, 0);
      } else if (t > 0){
        // optimistic data load -> flag wait (1 line) -> reload -> serial poll
        const u16* A = h0_all + (((long)(t-1)*2 + cell)*16 + rowA)*1024 + ko + kq8;
        f32x4 Af[8];
        G_LOAD8(Af, A);
        int ok = 1;
        #pragma unroll
        for (int i = 0; i < 8; i++) ok &= frag_ok(Af[i]);
        if (!__all(ok)){
          flag_wait(flr, l & 15, (u32)t);
          poll8(Af, A);
        }
        #pragma unroll
        for (int i = 0; i < 8; i++)
          #pragma unroll
          for (int g = 0; g < 4; g++)
            acc[g] = MFMA(__builtin_bit_cast(bf16x8, Af[i]),
                          __builtin_bit_cast(bf16x8, w[g][i]), acc[g], 0, 0, 0);
      }
      {
        int r0 = (l >> 4)*4, cj = l & 15;
        #pragma unroll
        for (int g = 0; g < 4; g++)
          #pragma unroll
          for (int i2 = 0; i2 < 4; i2++)
            gl[wv*1024 + g*256 + (r0+i2)*16 + cj] = acc[g][i2];
      }
      __syncthreads();                          // B: all 8 partials in gl
      if (tid < 256){
        float s0=0.f, s1=0.f, s2=0.f, s3=0.f;
        #pragma unroll
        for (int wq = 0; wq < 8; wq++){
          s0 += gl[wq*1024 + tid];
          s1 += gl[wq*1024 + 256 + tid];
          s2 += gl[wq*1024 + 512 + tid];
          s3 += gl[wq*1024 + 768 + tid];
        }
        float c2 = sigm(s1)*creg + sigm(s0)*tanh_(s2);
        float h2 = sigm(s3)*tanh_(c2);
        creg = c2;
        u32 lo = f2b(h2), hi = __shfl_down(lo, 1);
        if (!(tid & 1)){
          long idx = ((((long)t*2 + cell)*16 + b_)*1024 + jb*16 + j) >> 1;
          g_store32(hdst + idx, lo | (hi << 16));   // fire-and-forget
        }
      }
      __syncthreads();                          // C: gl safe to reuse
      if (tid == 0) g_store32(myf, (u32)(t+1));     // advisory flag, no drain
    }
  } else {
    // l1: per wave: h0 ks wv*8..+7 (regs), h1 ks 64+wv*4 (1 frag reg + 3 LDS)
    f32x4 wh0[4][8];
    f32x4 wh1[4];
    {
      const f32x4* src = (const f32x4*)W1p + ((long)(cell*64 + jb)*4)*96*64 + l;
      #pragma unroll
      for (int g = 0; g < 4; g++){
        #pragma unroll
        for (int i = 0; i < 8; i++)
          wh0[g][i] = src[((long)g*96 + wv*8 + i)*64];
        wh1[g] = src[((long)g*96 + 64 + wv*4)*64];
      }
      const f32x4* wb = (const f32x4*)W1p + ((long)(cell*64 + jb)*4)*96*64;
      for (int i = tid; i < 6144; i += 512){
        int g = i / 1536, r = (i % 1536) >> 6, ll = i & 63;
        int ksl = 64 + (r/3)*4 + (r%3) + 1;
        wlds[i] = wb[((long)g*96 + ksl)*64 + ll];
      }
    }
    #pragma unroll
    for (int g = 0; g < 4; g++){
      #pragma unroll
      for (int i = 0; i < 8; i++) asm volatile("" : "+v"(wh0[g][i]));
      asm volatile("" : "+v"(wh1[g]));
    }
    __syncthreads();

    u32* h1d = (u32*)h1r;
    u32* myf = flags + (2 + cell)*64 + jb;
    const u32* fl0 = flags + (wv >> 2)*64 + (wv & 3)*16;  // h0 producers (dir)
    const u32* flh = flags + (2 + cell)*64 + wv*8;        // h1 producers (8)

    for (int t = 0; t < TT; t++){
      // early-issue h1(t-1) attempt (hides under h0-part compute)
      f32x4 Bf[4];
      const u16* Ah = h1r + (((long)((t+3)&3)*2 + cell)*16 + rowA)*1024
                    + wv*128 + kq8;
      G_LOAD4_ISSUE(Bf, Ah);
      // reset slot (t+1)&3 (holds h1(t-3); provably unread). Drained by this
      // wave's own later vmcnt(0)s before that slot's next write.
      if (tid < 256 && !(tid & 1)){
        long idx = ((((long)((t+1)&3)*2 + cell)*16 + b_)*1024 + jb*16 + j) >> 1;
        g_store32(h1d + idx, 0xFFFFFFFFu);
      }
      // h0f/h0b(t): optimistic -> flag wait -> serial poll
      f32x4 acc[4];
      #pragma unroll
      for (int g = 0; g < 4; g++) acc[g] = (f32x4){bias[g],bias[g],bias[g],bias[g]};
      {
        const u16* A = h0_all + ((long)t*32 + (wv>>2)*16 + rowA)*1024
                     + (wv & 3)*256 + kq8;
        f32x4 Af[8];
        G_LOAD8(Af, A);
        int ok = 1;
        #pragma unroll
        for (int i = 0; i < 8; i++) ok &= frag_ok(Af[i]);
        if (!__all(ok)){
          flag_wait(fl0, l & 15, (u32)(t+1));
          poll8(Af, A);
        }
        #pragma unroll
        for (int i = 0; i < 8; i++)
          #pragma unroll
          for (int g = 0; g < 4; g++)
            acc[g] = MFMA(__builtin_bit_cast(bf16x8, Af[i]),
                          __builtin_bit_cast(bf16x8, wh0[g][i]), acc[g], 0, 0, 0);
      }
      // h1(t-1): verify early data; flag-assisted retry on sentinel
      G_WAIT4(Bf);
      {
        int ok = 1;
        #pragma unroll
        for (int i = 0; i < 4; i++) ok &= frag_ok(Bf[i]);
        if (!__all(ok)){
          flag_wait(flh, l & 7, (u32)t);
          for (;;){
            G_LOAD4W(Bf, Ah);
            ok = 1;
            #pragma unroll
            for (int i = 0; i < 4; i++) ok &= frag_ok(Bf[i]);
            if (__all(ok)) break;
          }
        }
      }
      #pragma unroll
      for (int i = 0; i < 4; i++)
        #pragma unroll
        for (int g = 0; g < 4; g++){
          f32x4 bw = (i == 0) ? wh1[g] : wlds[(g*24 + wv*3 + (i-1))*64 + l];
          acc[g] = MFMA(__builtin_bit_cast(bf16x8, Bf[i]),
                        __builtin_bit_cast(bf16x8, bw), acc[g], 0, 0, 0);
        }
      {
        int r0 = (l >> 4)*4, cj = l & 15;
        #pragma unroll
        for (int g = 0; g < 4; g++)
          #pragma unroll
          for (int i2 = 0; i2 < 4; i2++)
            gl[wv*1024 + g*256 + (r0+i2)*16 + cj] = acc[g][i2];
      }
      __syncthreads();                          // B: partials in gl
      if (tid < 256){
        float s0=0.f, s1=0.f, s2=0.f, s3=0.f;
        #pragma unroll
        for (int wq = 0; wq < 8; wq++){
          s0 += gl[wq*1024 + tid];
          s1 += gl[wq*1024 + 256 + tid];
          s2 += gl[wq*1024 + 512 + tid];
          s3 += gl[wq*1024 + 768 + tid];
        }
        float c2 = sigm(s1)*creg + sigm(s0)*tanh_(s2);
        float h2 = sigm(s3)*tanh_(c2);
        creg = c2;
        out[((long)b_*TT + t)*2048 + cell*1024 + jb*16 + j] = h2;
        u32 lo = f2b(h2), hi = __shfl_down(lo, 1);
        if (!(tid & 1)){
          long idx = ((((long)(t & 3)*2 + cell)*16 + b_)*1024 + jb*16 + j) >> 1;
          g_store32(h1d + idx, lo | (hi << 16));   // fire-and-forget
        }
      }
      __syncthreads();                          // C: gl safe to reuse
      if (tid == 0) g_store32(myf, (u32)(t+1));     // advisory flag, no drain
    }
  }
}

extern "C" void kernel_launch(void* const* d_in, const int* in_sizes, int n_in,
                              void* d_out, int out_size, void* d_ws, size_t ws_size,
                              hipStream_t stream){
  const int*   inputs = (const int*)d_in[0];
  const float* emb    = (const float*)d_in[1];
  const float* wih0   = (const float*)d_in[2];
  const float* whh0   = (const float*)d_in[3];
  const float* bih0   = (const float*)d_in[4];
  const float* bhh0   = (const float*)d_in[5];
  const float* wih1   = (const float*)d_in[6];
  const float* whh1   = (const float*)d_in[7];
  const float* bih1   = (const float*)d_in[8];
  const float* bhh1   = (const float*)d_in[9];
  float* out = (float*)d_out;
  char* ws = (char*)d_ws;

  u32*   flags = (u32*)(ws + OFS_FLAGS);
  float* b0    = (float*)(ws + OFS_B0);
  float* b1    = (float*)(ws + OFS_B1);
  u16*   Xb    = (u16*)(ws + OFS_X);
  u16*   Wih0p = (u16*)(ws + OFS_WIH0);
  u16*   Whh0p = (u16*)(ws + OFS_WHH0);
  u16*   W1p   = (u16*)(ws + OFS_W1);
  u16*   h0a   = (u16*)(ws + OFS_H0);
  u16*   h1r   = (u16*)(ws + OFS_H1);
  unsigned long long* h1z = (unsigned long long*)(ws + OFS_H1 + 196608ul);

  // zero flags; arm sentinels: h0 history + h1 slots 0-2 (slot 3 zeroed by k_bias)
  hipMemsetAsync(flags, 0, 4096, stream);
  hipMemsetAsync(ws + OFS_H0, 0xFF, 33554432ul, stream);
  hipMemsetAsync(ws + OFS_H1, 0xFF, 196608ul, stream);
  k_bias <<<32,   256, 0, stream>>>(bih0, bhh0, bih1, bhh1, b0, b1, h1z);
  k_embed<<<8192, 256, 0, stream>>>(inputs, emb, Xb);
  k_pack <<<4096, 256, 0, stream>>>(wih0, (const float*)0, 1024, 0, Wih0p);
  k_pack <<<4096, 256, 0, stream>>>(whh0, (const float*)0, 1024, 0, Whh0p);
  k_pack <<<12288,256, 0, stream>>>(wih1, whh1, 2048, 1024, W1p);

  const int smem_bytes = 32768 + 98304;   // gl 32KB + l1 h1-weight frags 96KB
  hipFuncSetAttribute(reinterpret_cast<const void*>(&k_fused),
                      hipFuncAttributeMaxDynamicSharedMemorySize, smem_bytes);
  k_fused<<<256, 512, smem_bytes, stream>>>(Wih0p, Whh0p, W1p, b0, b1, Xb,
                                            h0a, h1r, out, flags);
}